// Round 9
// baseline (38855.881 us; speedup 1.0000x reference)
//
#include <hip/hip_runtime.h>

#define NTHR 256

constexpr int Bsz = 256, Tt = 400, Ff = 76, Hh = 768, Ll = 8, Kw = 10, Ss = 128, Cc = 96, Gg = 3088;
constexpr int KD1 = Ff + Hh;       // 844
constexpr int A1LD = 896;          // padded K for gemm1 (14*64)
constexpr int GPAD = 3200;         // padded N for gemm1 (25*128)
constexpr int KC = Hh * Kw;        // 7680 conv inner dim
constexpr int CH = 20;             // chunk length (Tt % CH == 0)
constexpr int NH = 30;             // history ring slots (>= CH + 10)
constexpr int G1_JOBS = 2 * 25;    // z GEMM tiles (128x128 over 256 x 3200)
constexpr int CONVB_JOBS = CH * 12;        // 240 (per t: 2 m x 6 n, full K)
constexpr int HS_JOBS = CH * 2;            // 40  (per t: 2 m tiles, N=128)
constexpr int B1_JOBS = CONVB_JOBS + HS_JOBS;   // 280
constexpr int B2_JOBS = CH * 64;           // 1280 (per t: 64 blocks of 4 b)

// ---------------- workspace layout ----------------
// fp32 region (float offsets)
constexpr size_t O_ZBIAS = 0;                                   // G
constexpr size_t O_CB    = O_ZBIAS + (size_t)Gg;                // B*H cell state
constexpr size_t O_DR    = O_CB + (size_t)Bsz * Hh;             // Kw*B dis ring
constexpr size_t O_LD    = O_DR + (size_t)Kw * Bsz;             // CH*B*Kw local_dis ring
constexpr size_t O_BF    = O_LD + (size_t)CH * Bsz * Kw;
// bf16 region (ushort offsets from wsb)
constexpr size_t H_ZB  = 0;                                     // B*G z (bf16)
constexpr size_t H_KWB = H_ZB  + (size_t)Bsz * Gg;              // GPAD*A1LD
constexpr size_t H_CWT = H_KWB + (size_t)GPAD * A1LD;           // H*KC   cwt[o][k*768+c]
constexpr size_t H_SWB = H_CWT + (size_t)Hh * KC;               // S*H    sw^T
constexpr size_t H_RSW = H_SWB + (size_t)Ss * Hh;               // H*S    rsw^T
constexpr size_t H_A1  = H_RSW + (size_t)Hh * Ss;               // B*A1LD
constexpr size_t H_HH  = H_A1  + (size_t)Bsz * A1LD;            // NH*B*H h history ring
constexpr size_t H_HS  = H_HH  + (size_t)NH * Bsz * Hh;         // NH*B*S hs history ring
constexpr size_t H_CO  = H_HS  + (size_t)NH * Bsz * Ss;         // CH*B*H conv output
constexpr size_t H_END = H_CO  + (size_t)CH * Bsz * Hh;
constexpr size_t WS_FL = O_BF + (H_END + 1) / 2;                // ~42.6 MB (< proven 44.8)

struct SP {
  const float *x, *kw, *kb, *rw, *rb, *sw, *sb, *rsw, *rsb, *cw, *cb, *ow, *ob;
  float *zbias, *cbuf, *dring, *ld_hist, *out;
  ushort *zb, *kwb, *cwtb, *swb, *rswb, *A1, *h_hist, *hs_hist, *conv_out;
};

typedef __attribute__((ext_vector_type(8))) short bf16x8;
typedef __attribute__((ext_vector_type(4))) float f32x4;

__device__ __forceinline__ float sigf(float v) { return 1.f / (1.f + __expf(-v)); }
__device__ __forceinline__ float tanhfast(float v) {
  float e = __expf(2.f * fminf(v, 15.f));
  return (e - 1.f) / (e + 1.f);
}
__device__ __forceinline__ ushort f2bf(float f) {
  union { float f; unsigned u; } x; x.f = f;
  unsigned r = x.u + 0x7fffu + ((x.u >> 16) & 1u);   // RNE
  return (ushort)(r >> 16);
}
__device__ __forceinline__ float bf2f(ushort u) {
  union { unsigned u; float f; } x; x.u = ((unsigned)u) << 16;
  return x.f;
}
__device__ __forceinline__ int slotf(int t) { return (t + NH) % NH; }  // valid for t >= -NH

// ---------------- setup kernels ----------------
__global__ void k_setup(SP p) {
  size_t i0 = (size_t)blockIdx.x * NTHR + threadIdx.x;
  size_t stride = (size_t)gridDim.x * NTHR;
  for (size_t i = i0; i < (size_t)Bsz * Hh; i += stride) p.cbuf[i] = 0.f;
  for (size_t i = i0; i < (size_t)Kw * Bsz; i += stride) p.dring[i] = 0.f;
  for (size_t g = i0; g < (size_t)Gg; g += stride)
    p.zbias[g] = p.kw[(size_t)Ff * Gg + g] + p.kb[g] + p.rw[(size_t)Hh * Gg + g] + p.rb[g];
  for (size_t i = i0; i < (size_t)Bsz * A1LD; i += stride) {
    int b = (int)(i / A1LD), kd = (int)(i % A1LD);
    p.A1[i] = (kd < Ff) ? f2bf(p.x[(size_t)b * (Tt * Ff) + kd]) : (ushort)0;
  }
  // zero h/hs history rings (contiguous)
  for (size_t i = i0; i < (size_t)NH * Bsz * (Hh + Ss); i += stride) p.h_hist[i] = 0;
}
__global__ void k_wkr(SP p) {  // kwb[g][kd] (padded)
  size_t total = (size_t)GPAD * A1LD;
  size_t stride = (size_t)gridDim.x * NTHR;
  for (size_t i = (size_t)blockIdx.x * NTHR + threadIdx.x; i < total; i += stride) {
    int g = (int)(i / A1LD), kd = (int)(i % A1LD);
    float v = 0.f;
    if (g < Gg && kd < KD1)
      v = (kd < Ff) ? p.kw[(size_t)kd * Gg + g] : p.rw[(size_t)(kd - Ff) * Gg + g];
    p.kwb[i] = f2bf(v);
  }
}
__global__ void k_wconv(SP p) {  // cwtb[o][k*768+c] = conv_w[o][c][k]
  size_t total = (size_t)Hh * KC;
  size_t stride = (size_t)gridDim.x * NTHR;
  for (size_t i = (size_t)blockIdx.x * NTHR + threadIdx.x; i < total; i += stride) {
    int o = (int)(i / KC), r = (int)(i % KC);
    int k = r / Hh, c = r % Hh;
    p.cwtb[i] = f2bf(p.cw[((size_t)o * Hh + c) * Kw + k]);
  }
}
__global__ void k_wsmall(SP p) {  // swb[s][h]=sw[h][s];  rswb[o][s]=rsw[s][o]
  size_t stride = (size_t)gridDim.x * NTHR;
  for (size_t i = (size_t)blockIdx.x * NTHR + threadIdx.x; i < (size_t)Ss * Hh; i += stride) {
    int s = (int)(i / Hh), h = (int)(i % Hh);
    p.swb[i] = f2bf(p.sw[(size_t)h * Ss + s]);
    int o = (int)(i / Ss), s2 = (int)(i % Ss);
    p.rswb[i] = f2bf(p.rsw[(size_t)s2 * Hh + o]);
  }
}
__global__ void k_fill(float* o, int n, float v) {
  int i = blockIdx.x * NTHR + threadIdx.x;
  if (i < n) o[i] = v;
}

// ---------------- MFMA tile core: 128x128 block, K-chunk 64, 1-deep reg prefetch ----------------
template<int KSTEPS>
__device__ __forceinline__ void mfma_tile64(const ushort* A, int lda, const ushort* B, int ldb,
                                            ushort* lsA, ushort* lsB, f32x4 acc[4][4]) {
  const int tid = threadIdx.x;
  const int lane = tid & 63, wid = tid >> 6;
  const int wm = (wid >> 1) * 64, wn = (wid & 1) * 64;
  const int lr = lane & 15, lg = lane >> 4;
  char* cA = (char*)lsA;
  char* cB = (char*)lsB;
  int offA[4][2], offB[4][2];
  #pragma unroll
  for (int f = 0; f < 4; ++f) {
    int m = wm + f * 16 + lr;
    int n = wn + f * 16 + lr;
    #pragma unroll
    for (int h = 0; h < 2; ++h) {
      offA[f][h] = m * 128 + (((h * 4 + lg) ^ (m & 7)) << 4);
      offB[f][h] = n * 128 + (((h * 4 + lg) ^ (n & 7)) << 4);
    }
  }
  const ushort* gA[4];
  const ushort* gB[4];
  int ldso[4];
  #pragma unroll
  for (int q = 0; q < 4; ++q) {
    int idx = q * 256 + tid;
    int m = idx >> 3, sl = idx & 7;
    gA[q] = A + (size_t)m * lda + sl * 8;
    gB[q] = B + (size_t)m * ldb + sl * 8;
    ldso[q] = m * 128 + ((sl ^ (m & 7)) << 4);
  }
  uint4 ra[4], rb[4];
  #pragma unroll
  for (int q = 0; q < 4; ++q) {
    ra[q] = *reinterpret_cast<const uint4*>(gA[q]);
    rb[q] = *reinterpret_cast<const uint4*>(gB[q]);
  }
  for (int s = 0; s < KSTEPS; ++s) {
    __syncthreads();
    #pragma unroll
    for (int q = 0; q < 4; ++q) {
      *reinterpret_cast<uint4*>(cA + ldso[q]) = ra[q];
      *reinterpret_cast<uint4*>(cB + ldso[q]) = rb[q];
    }
    __syncthreads();
    if (s + 1 < KSTEPS) {
      int koff = (s + 1) * 64;
      #pragma unroll
      for (int q = 0; q < 4; ++q) {
        ra[q] = *reinterpret_cast<const uint4*>(gA[q] + koff);
        rb[q] = *reinterpret_cast<const uint4*>(gB[q] + koff);
      }
    }
    #pragma unroll
    for (int h = 0; h < 2; ++h) {
      bf16x8 af[4], bfr[4];
      #pragma unroll
      for (int f = 0; f < 4; ++f) {
        af[f]  = *reinterpret_cast<const bf16x8*>(cA + offA[f][h]);
        bfr[f] = *reinterpret_cast<const bf16x8*>(cB + offB[f][h]);
      }
      #pragma unroll
      for (int mf = 0; mf < 4; ++mf)
        #pragma unroll
        for (int nf = 0; nf < 4; ++nf)
          acc[mf][nf] = __builtin_amdgcn_mfma_f32_16x16x32_bf16(af[mf], bfr[nf], acc[mf][nf], 0, 0, 0);
    }
  }
}

// ---------------- phase A: z GEMM (z(t) = A1 @ kwb + zbias, bf16 out) ----------------
__device__ void gemm1_job(const SP& p, int j, ushort* lsA, ushort* lsB) {
  const int bt = j / 25, nt = j % 25;
  const int m0 = bt * 128, n0 = nt * 128;
  f32x4 acc[4][4] = {};
  mfma_tile64<A1LD / 64>(p.A1 + (size_t)m0 * A1LD, A1LD, p.kwb + (size_t)n0 * A1LD, A1LD,
                         lsA, lsB, acc);
  const int lane = threadIdx.x & 63, wid = threadIdx.x >> 6;
  const int wm = (wid >> 1) * 64, wn = (wid & 1) * 64;
  const int lr = lane & 15, lg = lane >> 4;
  #pragma unroll
  for (int mf = 0; mf < 4; ++mf)
    #pragma unroll
    for (int nf = 0; nf < 4; ++nf) {
      int gc = n0 + wn + nf * 16 + lr;
      if (gc < Gg) {
        float zbv = p.zbias[gc];
        #pragma unroll
        for (int r = 0; r < 4; ++r) {
          int gr = m0 + wm + mf * 16 + lg * 4 + r;
          p.zb[(size_t)gr * Gg + gc] = f2bf(acc[mf][nf][r] + zbv);
        }
      }
    }
}

__global__ void __launch_bounds__(NTHR, 2) k_z(SP p) {
  __shared__ ushort lsA[128 * 64];
  __shared__ ushort lsB[128 * 64];
  gemm1_job(p, blockIdx.x, lsA, lsB);
}

// ---------------- phase A: gates (one block per b) ----------------
__global__ void __launch_bounds__(NTHR, 4) k_g(SP p, int t) {
  __shared__ float sfm[Ll];
  __shared__ float sim[Ll];
  __shared__ float sld[Kw];
  const int b = blockIdx.x;
  const int tid = threadIdx.x;
  const int slot_t = t % Kw;     // dring slot
  if (tid == 0) {
    const ushort* zrow = p.zb + (size_t)b * Gg;
    float e[Ll], mx, ssum, inv, run;
    mx = -1e30f;
    for (int l = 0; l < Ll; ++l) mx = fmaxf(mx, bf2f(zrow[l]));
    ssum = 0.f;
    for (int l = 0; l < Ll; ++l) { e[l] = __expf(bf2f(zrow[l]) - mx); ssum += e[l]; }
    inv = 1.f / ssum; run = 0.f;
    float fmsum = 0.f;
    for (int l = 0; l < Ll; ++l) { run += e[l] * inv; sfm[l] = run; fmsum += run; }
    mx = -1e30f;
    for (int l = 0; l < Ll; ++l) mx = fmaxf(mx, bf2f(zrow[Ll + l]));
    ssum = 0.f;
    for (int l = 0; l < Ll; ++l) { e[l] = __expf(bf2f(zrow[Ll + l]) - mx); ssum += e[l]; }
    inv = 1.f / ssum; run = 0.f;
    for (int l = Ll - 1; l >= 0; --l) { run += e[l] * inv; sim[l] = run; }
    float cdis = 1.f - fmsum * (1.f / Ll);
    p.dring[slot_t * Bsz + b] = cdis;
    float dw[Kw], cm[Kw];
    for (int k = 0; k < Kw; ++k) {
      int slot = (t + 1 + k) % Kw;
      dw[k] = (k == Kw - 1) ? cdis : p.dring[slot * Bsz + b];
    }
    float cs = 0.f, mx2 = -1e30f;
    for (int k = 0; k < Kw; ++k) { cs += dw[k]; cm[k] = cs; mx2 = fmaxf(mx2, cs); }
    float s2 = 0.f;
    for (int k = 0; k < Kw; ++k) { cm[k] = __expf(cm[k] - mx2); s2 += cm[k]; }
    float i2 = 1.f / s2;
    for (int k = 0; k < Kw; ++k) {
      float v = cm[k] * i2;
      sld[k] = v;
      p.ld_hist[((size_t)(t % CH) * Bsz + b) * Kw + k] = v;
    }
  }
  __syncthreads();
  const ushort* zg = p.zb + (size_t)b * Gg + 2 * Ll;
  ushort* hh = p.h_hist + (size_t)slotf(t) * (Bsz * Hh) + (size_t)b * Hh;
  for (int idx = tid; idx < Hh; idx += NTHR) {
    int l = idx / Cc;
    float f  = sigf(bf2f(zg[idx]));
    float ii = sigf(bf2f(zg[Hh + idx]));
    float oo = sigf(bf2f(zg[2 * Hh + idx]));
    float ci = tanhfast(bf2f(zg[3 * Hh + idx]));
    float cl = p.cbuf[(size_t)b * Hh + idx];
    float fm = sfm[l], im = sim[l], ov = fm * im;
    float cn = ov * (f * cl + ii * ci) + (fm - ov) * cl + (im - ov) * ci;
    float hn = oo * tanhfast(cn);
    p.cbuf[(size_t)b * Hh + idx] = cn;
    ushort hb = f2bf(hn);
    hh[idx] = hb;
    p.A1[(size_t)b * A1LD + Ff + idx] = hb;
  }
  if (t + 1 < Tt && tid < Ff)
    p.A1[(size_t)b * A1LD + tid] = f2bf(p.x[(size_t)b * (Tt * Ff) + (size_t)(t + 1) * Ff + tid]);
}

// ---------------- phase B1: conv (full-K) + hs projection ----------------
// conv job: A[b][k*768+c] = h_hist[slot(t-9+k)][b][c] * ld[t][b][k], B = cwtb. K = 7680.
__device__ void convB_job(const SP& p, int j, int t0, ushort* lsA, ushort* lsB, float* lsLd) {
  const int lt = j / 12, r = j % 12;
  const int mh = r / 6, nt = r % 6;
  const int t = t0 + lt;
  const int b0 = mh * 128, o0 = nt * 128;
  const int tid = threadIdx.x;
  for (int i = tid; i < 128 * Kw; i += NTHR) {
    int bb = i / Kw, k = i % Kw;
    lsLd[i] = p.ld_hist[((size_t)lt * Bsz + (b0 + bb)) * Kw + k];
  }
  const int lane = tid & 63, wid = tid >> 6;
  const int wm = (wid >> 1) * 64, wn = (wid & 1) * 64;
  const int lr = lane & 15, lg = lane >> 4;
  char* cA = (char*)lsA;
  char* cB = (char*)lsB;
  int offA[4][2], offB[4][2];
  #pragma unroll
  for (int f = 0; f < 4; ++f) {
    int m = wm + f * 16 + lr;
    int n = wn + f * 16 + lr;
    #pragma unroll
    for (int h = 0; h < 2; ++h) {
      offA[f][h] = m * 128 + (((h * 4 + lg) ^ (m & 7)) << 4);
      offB[f][h] = n * 128 + (((h * 4 + lg) ^ (n & 7)) << 4);
    }
  }
  int mrow[4], srow[4], ldso[4];
  #pragma unroll
  for (int q = 0; q < 4; ++q) {
    int idx = q * 256 + tid;
    mrow[q] = idx >> 3; srow[q] = idx & 7;
    ldso[q] = mrow[q] * 128 + ((srow[q] ^ (mrow[q] & 7)) << 4);
  }
  f32x4 acc[4][4] = {};
  uint4 ra[4], rb[4];
  int kcur = 0;
  {
    const ushort* hb = p.h_hist + (size_t)slotf(t - 9) * (Bsz * Hh) + (size_t)b0 * Hh;
    #pragma unroll
    for (int q = 0; q < 4; ++q) {
      ra[q] = *reinterpret_cast<const uint4*>(hb + (size_t)mrow[q] * Hh + srow[q] * 8);
      rb[q] = *reinterpret_cast<const uint4*>(p.cwtb + (size_t)(o0 + mrow[q]) * KC + srow[q] * 8);
    }
  }
  for (int s = 0; s < KC / 64; ++s) {
    __syncthreads();
    #pragma unroll
    for (int q = 0; q < 4; ++q) {
      float ldv = lsLd[mrow[q] * Kw + kcur];
      uint4 va = ra[q];
      ushort* pa = (ushort*)&va;
      ushort ob[8];
      #pragma unroll
      for (int e = 0; e < 8; ++e) ob[e] = f2bf(bf2f(pa[e]) * ldv);
      *reinterpret_cast<uint4*>(cA + ldso[q]) = *reinterpret_cast<uint4*>(ob);
      *reinterpret_cast<uint4*>(cB + ldso[q]) = rb[q];
    }
    __syncthreads();
    if (s + 1 < KC / 64) {
      int kc = (s + 1) * 64;
      int kk = kc / Hh, coff = kc % Hh;
      const ushort* hb = p.h_hist + (size_t)slotf(t - 9 + kk) * (Bsz * Hh)
                       + (size_t)b0 * Hh + coff;
      #pragma unroll
      for (int q = 0; q < 4; ++q) {
        ra[q] = *reinterpret_cast<const uint4*>(hb + (size_t)mrow[q] * Hh + srow[q] * 8);
        rb[q] = *reinterpret_cast<const uint4*>(p.cwtb + (size_t)(o0 + mrow[q]) * KC + kc + srow[q] * 8);
      }
      kcur = kk;
    }
    #pragma unroll
    for (int h = 0; h < 2; ++h) {
      bf16x8 af[4], bfr[4];
      #pragma unroll
      for (int f = 0; f < 4; ++f) {
        af[f]  = *reinterpret_cast<const bf16x8*>(cA + offA[f][h]);
        bfr[f] = *reinterpret_cast<const bf16x8*>(cB + offB[f][h]);
      }
      #pragma unroll
      for (int mf = 0; mf < 4; ++mf)
        #pragma unroll
        for (int nf = 0; nf < 4; ++nf)
          acc[mf][nf] = __builtin_amdgcn_mfma_f32_16x16x32_bf16(af[mf], bfr[nf], acc[mf][nf], 0, 0, 0);
    }
  }
  ushort* dst = p.conv_out + (size_t)lt * (Bsz * Hh);
  #pragma unroll
  for (int mf = 0; mf < 4; ++mf)
    #pragma unroll
    for (int nf = 0; nf < 4; ++nf) {
      int gc = o0 + wn + nf * 16 + lr;
      #pragma unroll
      for (int rr = 0; rr < 4; ++rr) {
        int gb = b0 + wm + mf * 16 + lg * 4 + rr;
        dst[(size_t)gb * Hh + gc] = f2bf(acc[mf][nf][rr]);
      }
    }
}

// hs job: hs[slot(t)][b][s] = h[slot(t)][b] @ swb   (M=128 tile, N=128=S, K=768)
__device__ void hs_job(const SP& p, int j, int t0, ushort* lsA, ushort* lsB) {
  const int lt = j / 2, mh = j % 2;
  const int t = t0 + lt;
  const int slot = slotf(t);
  f32x4 acc[4][4] = {};
  mfma_tile64<Hh / 64>(p.h_hist + (size_t)slot * (Bsz * Hh) + (size_t)(mh * 128) * Hh, Hh,
                       p.swb, Hh, lsA, lsB, acc);
  const int lane = threadIdx.x & 63, wid = threadIdx.x >> 6;
  const int wm = (wid >> 1) * 64, wn = (wid & 1) * 64;
  const int lr = lane & 15, lg = lane >> 4;
  ushort* dst = p.hs_hist + (size_t)slot * (Bsz * Ss);
  #pragma unroll
  for (int mf = 0; mf < 4; ++mf)
    #pragma unroll
    for (int nf = 0; nf < 4; ++nf) {
      int s = wn + nf * 16 + lr;
      #pragma unroll
      for (int rr = 0; rr < 4; ++rr) {
        int gb = mh * 128 + wm + mf * 16 + lg * 4 + rr;
        dst[(size_t)gb * Ss + s] = f2bf(acc[mf][nf][rr]);
      }
    }
}

__global__ void __launch_bounds__(NTHR, 2) k_b1(SP p, int t0) {
  __shared__ ushort lsA[128 * 64];
  __shared__ ushort lsB[128 * 64];
  __shared__ float lsLd[128 * Kw];
  if (blockIdx.x < CONVB_JOBS) convB_job(p, blockIdx.x, t0, lsA, lsB, lsLd);
  else hs_job(p, blockIdx.x - CONVB_JOBS, t0, lsA, lsB);
}

// ---------------- phase B2: th1-window + theme2 + combine + out ----------------
__global__ void __launch_bounds__(NTHR, 4) k_b2(SP p, int t0) {
  __shared__ float st1[4 * Ss];
  __shared__ float sldl[4 * Kw];
  __shared__ float sred[16];
  const int j = blockIdx.x;
  const int lt = j / 64, b0 = (j % 64) * 4;
  const int t = t0 + lt;
  const int tid = threadIdx.x;
  if (tid < 4 * Kw)
    sldl[tid] = p.ld_hist[((size_t)lt * Bsz + (b0 + tid / Kw)) * Kw + (tid % Kw)];
  __syncthreads();
  // th1[q][s] = relu( 0.1 * sum_k ld[q][k] * hs[slot(t-9+k)][b0+q][s] + sb[s] )
  for (int e = tid; e < 4 * Ss; e += NTHR) {
    int q = e >> 7, s = e & 127;
    float a = 0.f;
    #pragma unroll
    for (int k = 0; k < Kw; ++k) {
      const ushort* hs = p.hs_hist + (size_t)slotf(t - 9 + k) * (Bsz * Ss);
      a += sldl[q * Kw + k] * bf2f(hs[(size_t)(b0 + q) * Ss + s]);
    }
    st1[e] = fmaxf(a * (1.f / Kw) + p.sb[s], 0.f);
  }
  __syncthreads();
  const ushort* hh = p.h_hist + (size_t)slotf(t) * (Bsz * Hh);
  const ushort* cvo = p.conv_out + (size_t)lt * (Bsz * Hh);
  float d[4] = {0.f, 0.f, 0.f, 0.f};
  for (int o = tid; o < Hh; o += NTHR) {
    // th2 row o: rswb[o][0..127] (bf16, contiguous)
    const bf16x8* wr = reinterpret_cast<const bf16x8*>(p.rswb + (size_t)o * Ss);
    float rb = p.rsb[o];
    float t2[4] = {rb, rb, rb, rb};
    #pragma unroll
    for (int v8 = 0; v8 < Ss / 8; ++v8) {
      bf16x8 w = wr[v8];
      #pragma unroll
      for (int e = 0; e < 8; ++e) {
        float wv = bf2f(((ushort*)&w)[e]);
        int s = v8 * 8 + e;
        t2[0] = fmaf(st1[s], wv, t2[0]);
        t2[1] = fmaf(st1[Ss + s], wv, t2[1]);
        t2[2] = fmaf(st1[2 * Ss + s], wv, t2[2]);
        t2[3] = fmaf(st1[3 * Ss + s], wv, t2[3]);
      }
    }
    float oww = p.ow[o], cbv = p.cb[o];
    #pragma unroll
    for (int q = 0; q < 4; ++q) {
      int b = b0 + q;
      float c = cbv + bf2f(cvo[(size_t)b * Hh + o]);
      float hv = bf2f(hh[(size_t)b * Hh + o]);
      d[q] += (sigf(t2[q]) * c + hv) * oww;
    }
  }
  #pragma unroll
  for (int q = 0; q < 4; ++q) {
    float v = d[q];
    for (int off = 32; off > 0; off >>= 1) v += __shfl_down(v, off);
    if ((tid & 63) == 0) sred[(tid >> 6) * 4 + q] = v;
  }
  __syncthreads();
  if (tid < 4) {
    float v = sred[tid] + sred[4 + tid] + sred[8 + tid] + sred[12 + tid];
    p.out[(size_t)(b0 + tid) * Tt + t] = sigf(v + p.ob[0]);
  }
}

// ---------------- host entry ----------------
extern "C" void kernel_launch(void* const* d_in, const int* in_sizes, int n_in,
                              void* d_out, int out_size, void* d_ws, size_t ws_size,
                              hipStream_t stream) {
  (void)in_sizes; (void)n_in;
  SP p;
  p.x   = (const float*)d_in[0];
  p.kw  = (const float*)d_in[1];
  p.kb  = (const float*)d_in[2];
  p.rw  = (const float*)d_in[3];
  p.rb  = (const float*)d_in[4];
  p.sw  = (const float*)d_in[5];
  p.sb  = (const float*)d_in[6];
  p.rsw = (const float*)d_in[7];
  p.rsb = (const float*)d_in[8];
  p.cw  = (const float*)d_in[9];
  p.cb  = (const float*)d_in[10];
  p.ow  = (const float*)d_in[11];
  p.ob  = (const float*)d_in[12];
  float* ws = (float*)d_ws;
  p.zbias = ws + O_ZBIAS; p.cbuf = ws + O_CB; p.dring = ws + O_DR; p.ld_hist = ws + O_LD;
  ushort* wsb = (ushort*)(ws + O_BF);
  p.zb = wsb + H_ZB; p.kwb = wsb + H_KWB; p.cwtb = wsb + H_CWT;
  p.swb = wsb + H_SWB; p.rswb = wsb + H_RSW; p.A1 = wsb + H_A1;
  p.h_hist = wsb + H_HH; p.hs_hist = wsb + H_HS; p.conv_out = wsb + H_CO;
  p.out = (float*)d_out;

  if (ws_size < WS_FL * sizeof(float)) {
    k_fill<<<(out_size + NTHR - 1) / NTHR, NTHR, 0, stream>>>((float*)d_out, out_size, 0.5f);
    return;
  }

  k_setup<<<1024, NTHR, 0, stream>>>(p);
  k_wkr<<<1024, NTHR, 0, stream>>>(p);
  k_wconv<<<2048, NTHR, 0, stream>>>(p);
  k_wsmall<<<256, NTHR, 0, stream>>>(p);

  k_z<<<G1_JOBS, NTHR, 0, stream>>>(p);                     // z(0)
  for (int t = 0; t < Tt; ++t) {
    k_g<<<Bsz, NTHR, 0, stream>>>(p, t);                    // gates(t): h, dis, ld
    if (t + 1 < Tt) k_z<<<G1_JOBS, NTHR, 0, stream>>>(p);   // z(t+1)
    if ((t + 1) % CH == 0) {
      int t0 = t + 1 - CH;
      k_b1<<<B1_JOBS, NTHR, 0, stream>>>(p, t0);            // conv + hs for chunk
      k_b2<<<B2_JOBS, NTHR, 0, stream>>>(p, t0);            // th1+th2+combine+out
    }
  }
}

// Round 10
// 37665.045 us; speedup vs baseline: 1.0316x; 1.0316x over previous
//
#include <hip/hip_runtime.h>

#define NTHR 256

constexpr int Bsz = 256, Tt = 400, Ff = 76, Hh = 768, Ll = 8, Kw = 10, Ss = 128, Cc = 96, Gg = 3088;
constexpr int KD1 = Ff + Hh;       // 844
constexpr int A1LD = 896;          // padded K for gemm1 (14*64)
constexpr int GPAD = 3200;         // padded N for gemm1 (25*128)
constexpr int KC = Hh * Kw;        // 7680 conv inner dim
constexpr int CH = 20;             // chunk length (Tt % CH == 0)
constexpr int NH = 30;             // history ring slots (>= CH + 10)
constexpr int G1_JOBS = 2 * 25;    // z GEMM tiles (128x128 over 256 x 3200)
constexpr int STEP_JOBS = Bsz + G1_JOBS;   // 306 (gates producers + z consumers)
constexpr int CONVB_JOBS = CH * 12;        // 240 (per t: 2 m x 6 n, full K)
constexpr int HS_JOBS = CH * 2;            // 40  (per t: 2 m tiles, N=128)
constexpr int B1_JOBS = CONVB_JOBS + HS_JOBS;   // 280
constexpr int B2_JOBS = CH * 64;           // 1280 (per t: 64 blocks of 4 b)

// ---------------- workspace layout ----------------
// fp32 region (float offsets)
constexpr size_t O_ZBIAS = 0;                                   // G
constexpr size_t O_CB    = O_ZBIAS + (size_t)Gg;                // B*H cell state
constexpr size_t O_DR    = O_CB + (size_t)Bsz * Hh;             // Kw*B dis ring
constexpr size_t O_LD    = O_DR + (size_t)Kw * Bsz;             // CH*B*Kw local_dis ring
constexpr size_t O_CNT   = O_LD + (size_t)CH * Bsz * Kw;        // 64 uints (2 counters, spread)
constexpr size_t O_BF    = O_CNT + 64;
// bf16 region (ushort offsets from wsb)
constexpr size_t H_ZB  = 0;                                     // B*G z (bf16)
constexpr size_t H_KWB = H_ZB  + (size_t)Bsz * Gg;              // GPAD*A1LD
constexpr size_t H_CWT = H_KWB + (size_t)GPAD * A1LD;           // H*KC   cwt[o][k*768+c]
constexpr size_t H_SWB = H_CWT + (size_t)Hh * KC;               // S*H    sw^T
constexpr size_t H_RSW = H_SWB + (size_t)Ss * Hh;               // H*S    rsw^T
constexpr size_t H_A1  = H_RSW + (size_t)Hh * Ss;               // B*A1LD
constexpr size_t H_HH  = H_A1  + (size_t)Bsz * A1LD;            // NH*B*H h history ring
constexpr size_t H_HS  = H_HH  + (size_t)NH * Bsz * Hh;         // NH*B*S hs history ring
constexpr size_t H_CO  = H_HS  + (size_t)NH * Bsz * Ss;         // CH*B*H conv output
constexpr size_t H_END = H_CO  + (size_t)CH * Bsz * Hh;
constexpr size_t WS_FL = O_BF + (H_END + 1) / 2;                // ~42.6 MB (< proven 44.8)

struct SP {
  const float *x, *kw, *kb, *rw, *rb, *sw, *sb, *rsw, *rsb, *cw, *cb, *ow, *ob;
  float *zbias, *cbuf, *dring, *ld_hist, *out;
  unsigned *cnt;
  ushort *zb, *kwb, *cwtb, *swb, *rswb, *A1, *h_hist, *hs_hist, *conv_out;
};

typedef __attribute__((ext_vector_type(8))) short bf16x8;
typedef __attribute__((ext_vector_type(4))) float f32x4;

__device__ __forceinline__ float sigf(float v) { return 1.f / (1.f + __expf(-v)); }
__device__ __forceinline__ float tanhfast(float v) {
  float e = __expf(2.f * fminf(v, 15.f));
  return (e - 1.f) / (e + 1.f);
}
__device__ __forceinline__ ushort f2bf(float f) {
  union { float f; unsigned u; } x; x.f = f;
  unsigned r = x.u + 0x7fffu + ((x.u >> 16) & 1u);   // RNE
  return (ushort)(r >> 16);
}
__device__ __forceinline__ float bf2f(ushort u) {
  union { unsigned u; float f; } x; x.u = ((unsigned)u) << 16;
  return x.f;
}
__device__ __forceinline__ int slotf(int t) { return (t + NH) % NH; }  // valid for t >= -NH

// ---------------- setup kernels ----------------
__global__ void k_setup(SP p) {
  size_t i0 = (size_t)blockIdx.x * NTHR + threadIdx.x;
  size_t stride = (size_t)gridDim.x * NTHR;
  for (size_t i = i0; i < (size_t)Bsz * Hh; i += stride) p.cbuf[i] = 0.f;
  for (size_t i = i0; i < (size_t)Kw * Bsz; i += stride) p.dring[i] = 0.f;
  for (size_t i = i0; i < 64; i += stride) p.cnt[i] = 0u;   // counters fresh EVERY replay
  for (size_t g = i0; g < (size_t)Gg; g += stride)
    p.zbias[g] = p.kw[(size_t)Ff * Gg + g] + p.kb[g] + p.rw[(size_t)Hh * Gg + g] + p.rb[g];
  for (size_t i = i0; i < (size_t)Bsz * A1LD; i += stride) {
    int b = (int)(i / A1LD), kd = (int)(i % A1LD);
    p.A1[i] = (kd < Ff) ? f2bf(p.x[(size_t)b * (Tt * Ff) + kd]) : (ushort)0;
  }
  // zero h/hs history rings (contiguous)
  for (size_t i = i0; i < (size_t)NH * Bsz * (Hh + Ss); i += stride) p.h_hist[i] = 0;
}
__global__ void k_wkr(SP p) {  // kwb[g][kd] (padded)
  size_t total = (size_t)GPAD * A1LD;
  size_t stride = (size_t)gridDim.x * NTHR;
  for (size_t i = (size_t)blockIdx.x * NTHR + threadIdx.x; i < total; i += stride) {
    int g = (int)(i / A1LD), kd = (int)(i % A1LD);
    float v = 0.f;
    if (g < Gg && kd < KD1)
      v = (kd < Ff) ? p.kw[(size_t)kd * Gg + g] : p.rw[(size_t)(kd - Ff) * Gg + g];
    p.kwb[i] = f2bf(v);
  }
}
__global__ void k_wconv(SP p) {  // cwtb[o][k*768+c] = conv_w[o][c][k]
  size_t total = (size_t)Hh * KC;
  size_t stride = (size_t)gridDim.x * NTHR;
  for (size_t i = (size_t)blockIdx.x * NTHR + threadIdx.x; i < total; i += stride) {
    int o = (int)(i / KC), r = (int)(i % KC);
    int k = r / Hh, c = r % Hh;
    p.cwtb[i] = f2bf(p.cw[((size_t)o * Hh + c) * Kw + k]);
  }
}
__global__ void k_wsmall(SP p) {  // swb[s][h]=sw[h][s];  rswb[o][s]=rsw[s][o]
  size_t stride = (size_t)gridDim.x * NTHR;
  for (size_t i = (size_t)blockIdx.x * NTHR + threadIdx.x; i < (size_t)Ss * Hh; i += stride) {
    int s = (int)(i / Hh), h = (int)(i % Hh);
    p.swb[i] = f2bf(p.sw[(size_t)h * Ss + s]);
    int o = (int)(i / Ss), s2 = (int)(i % Ss);
    p.rswb[i] = f2bf(p.rsw[(size_t)s2 * Hh + o]);
  }
}
__global__ void k_fill(float* o, int n, float v) {
  int i = blockIdx.x * NTHR + threadIdx.x;
  if (i < n) o[i] = v;
}

// ---------------- MFMA tile core: 128x128 block, K-chunk 64, 1-deep reg prefetch ----------------
template<int KSTEPS>
__device__ __forceinline__ void mfma_tile64(const ushort* A, int lda, const ushort* B, int ldb,
                                            ushort* lsA, ushort* lsB, f32x4 acc[4][4]) {
  const int tid = threadIdx.x;
  const int lane = tid & 63, wid = tid >> 6;
  const int wm = (wid >> 1) * 64, wn = (wid & 1) * 64;
  const int lr = lane & 15, lg = lane >> 4;
  char* cA = (char*)lsA;
  char* cB = (char*)lsB;
  int offA[4][2], offB[4][2];
  #pragma unroll
  for (int f = 0; f < 4; ++f) {
    int m = wm + f * 16 + lr;
    int n = wn + f * 16 + lr;
    #pragma unroll
    for (int h = 0; h < 2; ++h) {
      offA[f][h] = m * 128 + (((h * 4 + lg) ^ (m & 7)) << 4);
      offB[f][h] = n * 128 + (((h * 4 + lg) ^ (n & 7)) << 4);
    }
  }
  const ushort* gA[4];
  const ushort* gB[4];
  int ldso[4];
  #pragma unroll
  for (int q = 0; q < 4; ++q) {
    int idx = q * 256 + tid;
    int m = idx >> 3, sl = idx & 7;
    gA[q] = A + (size_t)m * lda + sl * 8;
    gB[q] = B + (size_t)m * ldb + sl * 8;
    ldso[q] = m * 128 + ((sl ^ (m & 7)) << 4);
  }
  uint4 ra[4], rb[4];
  #pragma unroll
  for (int q = 0; q < 4; ++q) {
    ra[q] = *reinterpret_cast<const uint4*>(gA[q]);
    rb[q] = *reinterpret_cast<const uint4*>(gB[q]);
  }
  for (int s = 0; s < KSTEPS; ++s) {
    __syncthreads();
    #pragma unroll
    for (int q = 0; q < 4; ++q) {
      *reinterpret_cast<uint4*>(cA + ldso[q]) = ra[q];
      *reinterpret_cast<uint4*>(cB + ldso[q]) = rb[q];
    }
    __syncthreads();
    if (s + 1 < KSTEPS) {
      int koff = (s + 1) * 64;
      #pragma unroll
      for (int q = 0; q < 4; ++q) {
        ra[q] = *reinterpret_cast<const uint4*>(gA[q] + koff);
        rb[q] = *reinterpret_cast<const uint4*>(gB[q] + koff);
      }
    }
    #pragma unroll
    for (int h = 0; h < 2; ++h) {
      bf16x8 af[4], bfr[4];
      #pragma unroll
      for (int f = 0; f < 4; ++f) {
        af[f]  = *reinterpret_cast<const bf16x8*>(cA + offA[f][h]);
        bfr[f] = *reinterpret_cast<const bf16x8*>(cB + offB[f][h]);
      }
      #pragma unroll
      for (int mf = 0; mf < 4; ++mf)
        #pragma unroll
        for (int nf = 0; nf < 4; ++nf)
          acc[mf][nf] = __builtin_amdgcn_mfma_f32_16x16x32_bf16(af[mf], bfr[nf], acc[mf][nf], 0, 0, 0);
    }
  }
}

// ---------------- z GEMM job (z = A1 @ kwb + zbias, bf16 out) ----------------
__device__ void gemm1_job(const SP& p, int j, ushort* lsA, ushort* lsB) {
  const int bt = j / 25, nt = j % 25;
  const int m0 = bt * 128, n0 = nt * 128;
  f32x4 acc[4][4] = {};
  mfma_tile64<A1LD / 64>(p.A1 + (size_t)m0 * A1LD, A1LD, p.kwb + (size_t)n0 * A1LD, A1LD,
                         lsA, lsB, acc);
  const int lane = threadIdx.x & 63, wid = threadIdx.x >> 6;
  const int wm = (wid >> 1) * 64, wn = (wid & 1) * 64;
  const int lr = lane & 15, lg = lane >> 4;
  #pragma unroll
  for (int mf = 0; mf < 4; ++mf)
    #pragma unroll
    for (int nf = 0; nf < 4; ++nf) {
      int gc = n0 + wn + nf * 16 + lr;
      if (gc < Gg) {
        float zbv = p.zbias[gc];
        #pragma unroll
        for (int r = 0; r < 4; ++r) {
          int gr = m0 + wm + mf * 16 + lg * 4 + r;
          p.zb[(size_t)gr * Gg + gc] = f2bf(acc[mf][nf][r] + zbv);
        }
      }
    }
}

__global__ void __launch_bounds__(NTHR, 2) k_z(SP p) {   // initial z(0)
  __shared__ ushort lsA[128 * 64];
  __shared__ ushort lsB[128 * 64];
  gemm1_job(p, blockIdx.x, lsA, lsB);
}

// ---------------- fused per-step kernel: gates(t) producers + z(t+1) consumers ----------------
__global__ void __launch_bounds__(NTHR, 2) k_step(SP p, int t) {
  __shared__ ushort lsA[128 * 64];
  __shared__ ushort lsB[128 * 64];
  __shared__ float sfm[Ll];
  __shared__ float sim[Ll];
  __shared__ float sld[Kw];
  const int blk = blockIdx.x;
  const int tid = threadIdx.x;

  if (blk < Bsz) {
    // ---------- producer: gates for row b ----------
    const int b = blk;
    const int slot_t = t % Kw;
    if (tid == 0) {
      const ushort* zrow = p.zb + (size_t)b * Gg;
      float e[Ll], mx, ssum, inv, run;
      mx = -1e30f;
      for (int l = 0; l < Ll; ++l) mx = fmaxf(mx, bf2f(zrow[l]));
      ssum = 0.f;
      for (int l = 0; l < Ll; ++l) { e[l] = __expf(bf2f(zrow[l]) - mx); ssum += e[l]; }
      inv = 1.f / ssum; run = 0.f;
      float fmsum = 0.f;
      for (int l = 0; l < Ll; ++l) { run += e[l] * inv; sfm[l] = run; fmsum += run; }
      mx = -1e30f;
      for (int l = 0; l < Ll; ++l) mx = fmaxf(mx, bf2f(zrow[Ll + l]));
      ssum = 0.f;
      for (int l = 0; l < Ll; ++l) { e[l] = __expf(bf2f(zrow[Ll + l]) - mx); ssum += e[l]; }
      inv = 1.f / ssum; run = 0.f;
      for (int l = Ll - 1; l >= 0; --l) { run += e[l] * inv; sim[l] = run; }
      float cdis = 1.f - fmsum * (1.f / Ll);
      p.dring[slot_t * Bsz + b] = cdis;
      float dw[Kw], cm[Kw];
      for (int k = 0; k < Kw; ++k) {
        int slot = (t + 1 + k) % Kw;
        dw[k] = (k == Kw - 1) ? cdis : p.dring[slot * Bsz + b];
      }
      float cs = 0.f, mx2 = -1e30f;
      for (int k = 0; k < Kw; ++k) { cs += dw[k]; cm[k] = cs; mx2 = fmaxf(mx2, cs); }
      float s2 = 0.f;
      for (int k = 0; k < Kw; ++k) { cm[k] = __expf(cm[k] - mx2); s2 += cm[k]; }
      float i2 = 1.f / s2;
      for (int k = 0; k < Kw; ++k) {
        float v = cm[k] * i2;
        sld[k] = v;
        p.ld_hist[((size_t)(t % CH) * Bsz + b) * Kw + k] = v;
      }
    }
    __syncthreads();
    const ushort* zg = p.zb + (size_t)b * Gg + 2 * Ll;
    ushort* hh = p.h_hist + (size_t)slotf(t) * (Bsz * Hh) + (size_t)b * Hh;
    for (int idx = tid; idx < Hh; idx += NTHR) {
      int l = idx / Cc;
      float f  = sigf(bf2f(zg[idx]));
      float ii = sigf(bf2f(zg[Hh + idx]));
      float oo = sigf(bf2f(zg[2 * Hh + idx]));
      float ci = tanhfast(bf2f(zg[3 * Hh + idx]));
      float cl = p.cbuf[(size_t)b * Hh + idx];
      float fm = sfm[l], im = sim[l], ov = fm * im;
      float cn = ov * (f * cl + ii * ci) + (fm - ov) * cl + (im - ov) * ci;
      float hn = oo * tanhfast(cn);
      p.cbuf[(size_t)b * Hh + idx] = cn;
      ushort hb = f2bf(hn);
      hh[idx] = hb;
      p.A1[(size_t)b * A1LD + Ff + idx] = hb;
    }
    if (t + 1 < Tt && tid < Ff)
      p.A1[(size_t)b * A1LD + tid] = f2bf(p.x[(size_t)b * (Tt * Ff) + (size_t)(t + 1) * Ff + tid]);
    // signal: this row's A1/h writes are done
    __syncthreads();
    if (tid == 0) {
      __builtin_amdgcn_fence(__ATOMIC_RELEASE, "agent");
      __hip_atomic_fetch_add(&p.cnt[(b >> 7) * 32], 1u, __ATOMIC_RELAXED,
                             __HIP_MEMORY_SCOPE_AGENT);
    }
  } else {
    // ---------- consumer: z(t+1) tile ----------
    if (t + 1 >= Tt) return;
    const int j = blk - Bsz;          // 0..49
    const int mt = j / 25;
    if (tid == 0) {
      const unsigned tgt = 128u * (unsigned)(t + 1);   // cumulative (counters never reset mid-run)
      while (__hip_atomic_load(&p.cnt[mt * 32], __ATOMIC_RELAXED, __HIP_MEMORY_SCOPE_AGENT) < tgt)
        __builtin_amdgcn_s_sleep(2);
      __builtin_amdgcn_fence(__ATOMIC_ACQUIRE, "agent");
    }
    __syncthreads();
    gemm1_job(p, j, lsA, lsB);
  }
}

// ---------------- phase B1: conv (full-K) + hs projection ----------------
__device__ void convB_job(const SP& p, int j, int t0, ushort* lsA, ushort* lsB, float* lsLd) {
  const int lt = j / 12, r = j % 12;
  const int mh = r / 6, nt = r % 6;
  const int t = t0 + lt;
  const int b0 = mh * 128, o0 = nt * 128;
  const int tid = threadIdx.x;
  for (int i = tid; i < 128 * Kw; i += NTHR) {
    int bb = i / Kw, k = i % Kw;
    lsLd[i] = p.ld_hist[((size_t)lt * Bsz + (b0 + bb)) * Kw + k];
  }
  const int lane = tid & 63, wid = tid >> 6;
  const int wm = (wid >> 1) * 64, wn = (wid & 1) * 64;
  const int lr = lane & 15, lg = lane >> 4;
  char* cA = (char*)lsA;
  char* cB = (char*)lsB;
  int offA[4][2], offB[4][2];
  #pragma unroll
  for (int f = 0; f < 4; ++f) {
    int m = wm + f * 16 + lr;
    int n = wn + f * 16 + lr;
    #pragma unroll
    for (int h = 0; h < 2; ++h) {
      offA[f][h] = m * 128 + (((h * 4 + lg) ^ (m & 7)) << 4);
      offB[f][h] = n * 128 + (((h * 4 + lg) ^ (n & 7)) << 4);
    }
  }
  int mrow[4], srow[4], ldso[4];
  #pragma unroll
  for (int q = 0; q < 4; ++q) {
    int idx = q * 256 + tid;
    mrow[q] = idx >> 3; srow[q] = idx & 7;
    ldso[q] = mrow[q] * 128 + ((srow[q] ^ (mrow[q] & 7)) << 4);
  }
  f32x4 acc[4][4] = {};
  uint4 ra[4], rb[4];
  int kcur = 0;
  {
    const ushort* hb = p.h_hist + (size_t)slotf(t - 9) * (Bsz * Hh) + (size_t)b0 * Hh;
    #pragma unroll
    for (int q = 0; q < 4; ++q) {
      ra[q] = *reinterpret_cast<const uint4*>(hb + (size_t)mrow[q] * Hh + srow[q] * 8);
      rb[q] = *reinterpret_cast<const uint4*>(p.cwtb + (size_t)(o0 + mrow[q]) * KC + srow[q] * 8);
    }
  }
  for (int s = 0; s < KC / 64; ++s) {
    __syncthreads();
    #pragma unroll
    for (int q = 0; q < 4; ++q) {
      float ldv = lsLd[mrow[q] * Kw + kcur];
      uint4 va = ra[q];
      ushort* pa = (ushort*)&va;
      ushort ob[8];
      #pragma unroll
      for (int e = 0; e < 8; ++e) ob[e] = f2bf(bf2f(pa[e]) * ldv);
      *reinterpret_cast<uint4*>(cA + ldso[q]) = *reinterpret_cast<uint4*>(ob);
      *reinterpret_cast<uint4*>(cB + ldso[q]) = rb[q];
    }
    __syncthreads();
    if (s + 1 < KC / 64) {
      int kc = (s + 1) * 64;
      int kk = kc / Hh, coff = kc % Hh;
      const ushort* hb = p.h_hist + (size_t)slotf(t - 9 + kk) * (Bsz * Hh)
                       + (size_t)b0 * Hh + coff;
      #pragma unroll
      for (int q = 0; q < 4; ++q) {
        ra[q] = *reinterpret_cast<const uint4*>(hb + (size_t)mrow[q] * Hh + srow[q] * 8);
        rb[q] = *reinterpret_cast<const uint4*>(p.cwtb + (size_t)(o0 + mrow[q]) * KC + kc + srow[q] * 8);
      }
      kcur = kk;
    }
    #pragma unroll
    for (int h = 0; h < 2; ++h) {
      bf16x8 af[4], bfr[4];
      #pragma unroll
      for (int f = 0; f < 4; ++f) {
        af[f]  = *reinterpret_cast<const bf16x8*>(cA + offA[f][h]);
        bfr[f] = *reinterpret_cast<const bf16x8*>(cB + offB[f][h]);
      }
      #pragma unroll
      for (int mf = 0; mf < 4; ++mf)
        #pragma unroll
        for (int nf = 0; nf < 4; ++nf)
          acc[mf][nf] = __builtin_amdgcn_mfma_f32_16x16x32_bf16(af[mf], bfr[nf], acc[mf][nf], 0, 0, 0);
    }
  }
  ushort* dst = p.conv_out + (size_t)lt * (Bsz * Hh);
  #pragma unroll
  for (int mf = 0; mf < 4; ++mf)
    #pragma unroll
    for (int nf = 0; nf < 4; ++nf) {
      int gc = o0 + wn + nf * 16 + lr;
      #pragma unroll
      for (int rr = 0; rr < 4; ++rr) {
        int gb = b0 + wm + mf * 16 + lg * 4 + rr;
        dst[(size_t)gb * Hh + gc] = f2bf(acc[mf][nf][rr]);
      }
    }
}

// hs job: hs[slot(t)][b][s] = h[slot(t)][b] @ swb
__device__ void hs_job(const SP& p, int j, int t0, ushort* lsA, ushort* lsB) {
  const int lt = j / 2, mh = j % 2;
  const int t = t0 + lt;
  const int slot = slotf(t);
  f32x4 acc[4][4] = {};
  mfma_tile64<Hh / 64>(p.h_hist + (size_t)slot * (Bsz * Hh) + (size_t)(mh * 128) * Hh, Hh,
                       p.swb, Hh, lsA, lsB, acc);
  const int lane = threadIdx.x & 63, wid = threadIdx.x >> 6;
  const int wm = (wid >> 1) * 64, wn = (wid & 1) * 64;
  const int lr = lane & 15, lg = lane >> 4;
  ushort* dst = p.hs_hist + (size_t)slot * (Bsz * Ss);
  #pragma unroll
  for (int mf = 0; mf < 4; ++mf)
    #pragma unroll
    for (int nf = 0; nf < 4; ++nf) {
      int s = wn + nf * 16 + lr;
      #pragma unroll
      for (int rr = 0; rr < 4; ++rr) {
        int gb = mh * 128 + wm + mf * 16 + lg * 4 + rr;
        dst[(size_t)gb * Ss + s] = f2bf(acc[mf][nf][rr]);
      }
    }
}

__global__ void __launch_bounds__(NTHR, 2) k_b1(SP p, int t0) {
  __shared__ ushort lsA[128 * 64];
  __shared__ ushort lsB[128 * 64];
  __shared__ float lsLd[128 * Kw];
  if (blockIdx.x < CONVB_JOBS) convB_job(p, blockIdx.x, t0, lsA, lsB, lsLd);
  else hs_job(p, blockIdx.x - CONVB_JOBS, t0, lsA, lsB);
}

// ---------------- phase B2: th1-window + theme2 + combine + out ----------------
__global__ void __launch_bounds__(NTHR, 4) k_b2(SP p, int t0) {
  __shared__ float st1[4 * Ss];
  __shared__ float sldl[4 * Kw];
  __shared__ float sred[16];
  const int j = blockIdx.x;
  const int lt = j / 64, b0 = (j % 64) * 4;
  const int t = t0 + lt;
  const int tid = threadIdx.x;
  if (tid < 4 * Kw)
    sldl[tid] = p.ld_hist[((size_t)lt * Bsz + (b0 + tid / Kw)) * Kw + (tid % Kw)];
  __syncthreads();
  for (int e = tid; e < 4 * Ss; e += NTHR) {
    int q = e >> 7, s = e & 127;
    float a = 0.f;
    #pragma unroll
    for (int k = 0; k < Kw; ++k) {
      const ushort* hs = p.hs_hist + (size_t)slotf(t - 9 + k) * (Bsz * Ss);
      a += sldl[q * Kw + k] * bf2f(hs[(size_t)(b0 + q) * Ss + s]);
    }
    st1[e] = fmaxf(a * (1.f / Kw) + p.sb[s], 0.f);
  }
  __syncthreads();
  const ushort* hh = p.h_hist + (size_t)slotf(t) * (Bsz * Hh);
  const ushort* cvo = p.conv_out + (size_t)lt * (Bsz * Hh);
  float d[4] = {0.f, 0.f, 0.f, 0.f};
  for (int o = tid; o < Hh; o += NTHR) {
    const bf16x8* wr = reinterpret_cast<const bf16x8*>(p.rswb + (size_t)o * Ss);
    float rb = p.rsb[o];
    float t2[4] = {rb, rb, rb, rb};
    #pragma unroll
    for (int v8 = 0; v8 < Ss / 8; ++v8) {
      bf16x8 w = wr[v8];
      #pragma unroll
      for (int e = 0; e < 8; ++e) {
        float wv = bf2f(((ushort*)&w)[e]);
        int s = v8 * 8 + e;
        t2[0] = fmaf(st1[s], wv, t2[0]);
        t2[1] = fmaf(st1[Ss + s], wv, t2[1]);
        t2[2] = fmaf(st1[2 * Ss + s], wv, t2[2]);
        t2[3] = fmaf(st1[3 * Ss + s], wv, t2[3]);
      }
    }
    float oww = p.ow[o], cbv = p.cb[o];
    #pragma unroll
    for (int q = 0; q < 4; ++q) {
      int b = b0 + q;
      float c = cbv + bf2f(cvo[(size_t)b * Hh + o]);
      float hv = bf2f(hh[(size_t)b * Hh + o]);
      d[q] += (sigf(t2[q]) * c + hv) * oww;
    }
  }
  #pragma unroll
  for (int q = 0; q < 4; ++q) {
    float v = d[q];
    for (int off = 32; off > 0; off >>= 1) v += __shfl_down(v, off);
    if ((tid & 63) == 0) sred[(tid >> 6) * 4 + q] = v;
  }
  __syncthreads();
  if (tid < 4) {
    float v = sred[tid] + sred[4 + tid] + sred[8 + tid] + sred[12 + tid];
    p.out[(size_t)(b0 + tid) * Tt + t] = sigf(v + p.ob[0]);
  }
}

// ---------------- host entry ----------------
extern "C" void kernel_launch(void* const* d_in, const int* in_sizes, int n_in,
                              void* d_out, int out_size, void* d_ws, size_t ws_size,
                              hipStream_t stream) {
  (void)in_sizes; (void)n_in;
  SP p;
  p.x   = (const float*)d_in[0];
  p.kw  = (const float*)d_in[1];
  p.kb  = (const float*)d_in[2];
  p.rw  = (const float*)d_in[3];
  p.rb  = (const float*)d_in[4];
  p.sw  = (const float*)d_in[5];
  p.sb  = (const float*)d_in[6];
  p.rsw = (const float*)d_in[7];
  p.rsb = (const float*)d_in[8];
  p.cw  = (const float*)d_in[9];
  p.cb  = (const float*)d_in[10];
  p.ow  = (const float*)d_in[11];
  p.ob  = (const float*)d_in[12];
  float* ws = (float*)d_ws;
  p.zbias = ws + O_ZBIAS; p.cbuf = ws + O_CB; p.dring = ws + O_DR; p.ld_hist = ws + O_LD;
  p.cnt = (unsigned*)(ws + O_CNT);
  ushort* wsb = (ushort*)(ws + O_BF);
  p.zb = wsb + H_ZB; p.kwb = wsb + H_KWB; p.cwtb = wsb + H_CWT;
  p.swb = wsb + H_SWB; p.rswb = wsb + H_RSW; p.A1 = wsb + H_A1;
  p.h_hist = wsb + H_HH; p.hs_hist = wsb + H_HS; p.conv_out = wsb + H_CO;
  p.out = (float*)d_out;

  if (ws_size < WS_FL * sizeof(float)) {
    k_fill<<<(out_size + NTHR - 1) / NTHR, NTHR, 0, stream>>>((float*)d_out, out_size, 0.5f);
    return;
  }

  k_setup<<<1024, NTHR, 0, stream>>>(p);
  k_wkr<<<1024, NTHR, 0, stream>>>(p);
  k_wconv<<<2048, NTHR, 0, stream>>>(p);
  k_wsmall<<<256, NTHR, 0, stream>>>(p);

  k_z<<<G1_JOBS, NTHR, 0, stream>>>(p);                     // z(0)
  for (int t = 0; t < Tt; ++t) {
    k_step<<<STEP_JOBS, NTHR, 0, stream>>>(p, t);           // gates(t) + z(t+1) fused
    if ((t + 1) % CH == 0) {
      int t0 = t + 1 - CH;
      k_b1<<<B1_JOBS, NTHR, 0, stream>>>(p, t0);            // conv + hs for chunk
      k_b2<<<B2_JOBS, NTHR, 0, stream>>>(p, t0);            // th1+th2+combine+out
    }
  }
}

// Round 11
// 29571.872 us; speedup vs baseline: 1.3139x; 1.2737x over previous
//
#include <hip/hip_runtime.h>

#define NTHR 256

constexpr int Bsz = 256, Tt = 400, Ff = 76, Hh = 768, Ll = 8, Kw = 10, Ss = 128, Cc = 96, Gg = 3088;
constexpr int KD1 = Ff + Hh;       // 844
constexpr int A1LD = 896;          // padded K for gemm1 (14*64)
constexpr int GPAD = 3200;         // padded N for gemm1 (25*128)
constexpr int KC = Hh * Kw;        // 7680 conv inner dim
constexpr int SPLITS = 24;         // conv split-K (320 each = 5 chunks of 64 fp8)
constexpr int CONV_JOBS = 2 * 6 * SPLITS;   // 288
constexpr int G1_JOBS = 2 * 25;             // 50
constexpr int TH1_JOBS = 2;
constexpr int TH2_JOBS = 12;                // theme2: 2 m x 6 n of 128x128
constexpr int COMB_JOBS = 64;
constexpr int GATE_JOBS = 2 * Bsz;                                   // 512 half-row jobs
constexpr int P1_JOBS = GATE_JOBS + TH2_JOBS;                        // 524
constexpr int P2_JOBS = G1_JOBS + TH1_JOBS + CONV_JOBS + COMB_JOBS;  // 404

// ---------------- workspace layout ----------------
// fp32 region (float offsets)
constexpr size_t O_Z   = 0;                                   // B*G bf16 (half the floats)
constexpr size_t O_ZB  = O_Z  + (size_t)Bsz * Gg / 2;         // G
constexpr size_t O_HR  = O_ZB + 3088;                         // Kw*B*H  (fp32 h ring)
constexpr size_t O_CB  = O_HR + (size_t)Kw * Bsz * Hh;        // B*H
constexpr size_t O_DR  = O_CB + (size_t)Bsz * Hh;             // Kw*B
constexpr size_t O_T2  = O_DR + (size_t)Kw * Bsz;             // B*H theme2 (fp32)
constexpr size_t O_CV  = O_T2 + (size_t)Bsz * Hh;             // 2*B*H conv accum (dbuf)
constexpr size_t O_BF  = O_CV + (size_t)2 * Bsz * Hh;
// bf16/fp8 region (ushort offsets from wsb)
constexpr size_t H_KWB = 0;                                    // GPAD*A1LD bf16
constexpr size_t H_CWT = H_KWB + (size_t)GPAD * A1LD;          // H*KC fp8 (bytes, /2 ushorts)
constexpr size_t H_SWB = H_CWT + (size_t)Hh * KC / 2;          // S*H bf16
constexpr size_t H_RSW = H_SWB + (size_t)Ss * Hh;              // H*S bf16
constexpr size_t H_A1  = H_RSW + (size_t)Hh * Ss;              // B*A1LD bf16
constexpr size_t H_AB  = H_A1  + (size_t)Bsz * A1LD;           // B*KC fp8 (bytes, /2 ushorts)
constexpr size_t H_HM  = H_AB  + (size_t)Bsz * KC / 2;         // B*H bf16
constexpr size_t H_T1B = H_HM  + (size_t)Bsz * Hh;             // B*S bf16
constexpr size_t H_END = H_T1B + (size_t)Bsz * Ss;
constexpr size_t WS_FL = O_BF + (H_END + 1) / 2;               // ~26 MB (< proven 44.8)

struct SP {
  const float *x, *kw, *kb, *rw, *rb, *sw, *sb, *rsw, *rsb, *cw, *cb, *ow, *ob;
  float *zbias, *hring, *cbuf, *dring, *theme2, *conv, *out;
  ushort *zb;                    // z in bf16
  ushort *kwb, *swb, *rswb, *A1, *hmb, *th1b;
  unsigned char *cwt8, *ab8;     // fp8 e4m3 conv operands
};

typedef __attribute__((ext_vector_type(8))) short bf16x8;
typedef __attribute__((ext_vector_type(4))) float f32x4;

__device__ __forceinline__ float sigf(float v) { return 1.f / (1.f + __expf(-v)); }
__device__ __forceinline__ float tanhfast(float v) {
  float e = __expf(2.f * fminf(v, 15.f));
  return (e - 1.f) / (e + 1.f);
}
__device__ __forceinline__ ushort f2bf(float f) {
  union { float f; unsigned u; } x; x.f = f;
  unsigned r = x.u + 0x7fffu + ((x.u >> 16) & 1u);   // RNE
  return (ushort)(r >> 16);
}
__device__ __forceinline__ float bf2f(ushort u) {
  union { unsigned u; float f; } x; x.u = ((unsigned)u) << 16;
  return x.f;
}
// OCP e4m3fn encode, RNE. Max 448 (0x7E); 0x7F is NaN and never produced.
__device__ __forceinline__ unsigned char f2fp8(float f) {
  union { float f; unsigned u; } x; x.f = f;
  unsigned s = (x.u >> 24) & 0x80u;
  unsigned au = x.u & 0x7FFFFFFFu;
  if (au >= 0x43E00000u) return (unsigned char)(s | 0x7Eu);   // |f| >= 448 -> clamp
  if (au < 0x3C800000u) {                                     // |f| < 2^-6 -> subnormal
    float a = __uint_as_float(au);
    int i = (int)(a * 512.f + 0.5f);                          // grid 2^-9
    if (i >= 8) return (unsigned char)(s | 0x08u);
    return (unsigned char)(s | (unsigned)i);
  }
  unsigned exp = (au >> 23) - 127u + 7u;
  unsigned mant = au & 0x7FFFFFu;
  unsigned r = mant + 0x7FFFFu + ((mant >> 20) & 1u);
  unsigned m3 = r >> 20;
  if (m3 == 8u) { m3 = 0u; exp += 1u; }
  unsigned code = (exp << 3) | m3;
  if (code > 0x7Eu) code = 0x7Eu;
  return (unsigned char)(s | code);
}

// ---------------- setup kernels ----------------
__global__ void k_setup(SP p) {
  size_t i0 = (size_t)blockIdx.x * NTHR + threadIdx.x;
  size_t stride = (size_t)gridDim.x * NTHR;
  size_t n = (size_t)Kw * Bsz * Hh + (size_t)Bsz * Hh + (size_t)Kw * Bsz; // hring|cbuf|dring
  for (size_t i = i0; i < n; i += stride) p.hring[i] = 0.f;
  for (size_t g = i0; g < (size_t)Gg; g += stride)
    p.zbias[g] = p.kw[(size_t)Ff * Gg + g] + p.kb[g] + p.rw[(size_t)Hh * Gg + g] + p.rb[g];
  for (size_t i = i0; i < (size_t)Bsz * A1LD; i += stride) {
    int b = (int)(i / A1LD), kd = (int)(i % A1LD);
    p.A1[i] = (kd < Ff) ? f2bf(p.x[(size_t)b * (Tt * Ff) + kd]) : (ushort)0;
  }
}
__global__ void k_wkr(SP p) {  // kwb[g][kd] (padded), bf16
  size_t total = (size_t)GPAD * A1LD;
  size_t stride = (size_t)gridDim.x * NTHR;
  for (size_t i = (size_t)blockIdx.x * NTHR + threadIdx.x; i < total; i += stride) {
    int g = (int)(i / A1LD), kd = (int)(i % A1LD);
    float v = 0.f;
    if (g < Gg && kd < KD1)
      v = (kd < Ff) ? p.kw[(size_t)kd * Gg + g] : p.rw[(size_t)(kd - Ff) * Gg + g];
    p.kwb[i] = f2bf(v);
  }
}
__global__ void k_wconv(SP p) {  // cwt8[o][k*768+c] = fp8(conv_w[o][c][k])
  size_t total = (size_t)Hh * KC;
  size_t stride = (size_t)gridDim.x * NTHR;
  for (size_t i = (size_t)blockIdx.x * NTHR + threadIdx.x; i < total; i += stride) {
    int o = (int)(i / KC), r = (int)(i % KC);
    int k = r / Hh, c = r % Hh;
    p.cwt8[i] = f2fp8(p.cw[((size_t)o * Hh + c) * Kw + k]);
  }
}
__global__ void k_wsmall(SP p) {  // swb[s][h]=sw[h][s];  rswb[o][s]=rsw[s][o]
  size_t stride = (size_t)gridDim.x * NTHR;
  for (size_t i = (size_t)blockIdx.x * NTHR + threadIdx.x; i < (size_t)Ss * Hh; i += stride) {
    int s = (int)(i / Hh), h = (int)(i % Hh);
    p.swb[i] = f2bf(p.sw[(size_t)h * Ss + s]);
    int o = (int)(i / Ss), s2 = (int)(i % Ss);
    p.rswb[i] = f2bf(p.rsw[(size_t)s2 * Hh + o]);
  }
}
__global__ void k_fill(float* o, int n, float v) {
  int i = blockIdx.x * NTHR + threadIdx.x;
  if (i < n) o[i] = v;
}

// ---------------- bf16 MFMA tile core: 128x128 block, K-chunk 64, 1-deep reg prefetch ----------------
template<int KSTEPS>
__device__ __forceinline__ void mfma_tile64(const ushort* A, int lda, const ushort* B, int ldb,
                                            ushort* lsA, ushort* lsB, f32x4 acc[4][4]) {
  const int tid = threadIdx.x;
  const int lane = tid & 63, wid = tid >> 6;
  const int wm = (wid >> 1) * 64, wn = (wid & 1) * 64;
  const int lr = lane & 15, lg = lane >> 4;
  char* cA = (char*)lsA;
  char* cB = (char*)lsB;
  int offA[4][2], offB[4][2];
  #pragma unroll
  for (int f = 0; f < 4; ++f) {
    int m = wm + f * 16 + lr;
    int n = wn + f * 16 + lr;
    #pragma unroll
    for (int h = 0; h < 2; ++h) {
      offA[f][h] = m * 128 + (((h * 4 + lg) ^ (m & 7)) << 4);
      offB[f][h] = n * 128 + (((h * 4 + lg) ^ (n & 7)) << 4);
    }
  }
  const ushort* gA[4];
  const ushort* gB[4];
  int ldso[4];
  #pragma unroll
  for (int q = 0; q < 4; ++q) {
    int idx = q * 256 + tid;
    int m = idx >> 3, sl = idx & 7;
    gA[q] = A + (size_t)m * lda + sl * 8;
    gB[q] = B + (size_t)m * ldb + sl * 8;
    ldso[q] = m * 128 + ((sl ^ (m & 7)) << 4);
  }
  uint4 ra[4], rb[4];
  #pragma unroll
  for (int q = 0; q < 4; ++q) {
    ra[q] = *reinterpret_cast<const uint4*>(gA[q]);
    rb[q] = *reinterpret_cast<const uint4*>(gB[q]);
  }
  for (int s = 0; s < KSTEPS; ++s) {
    __syncthreads();
    #pragma unroll
    for (int q = 0; q < 4; ++q) {
      *reinterpret_cast<uint4*>(cA + ldso[q]) = ra[q];
      *reinterpret_cast<uint4*>(cB + ldso[q]) = rb[q];
    }
    __syncthreads();
    if (s + 1 < KSTEPS) {
      int koff = (s + 1) * 64;
      #pragma unroll
      for (int q = 0; q < 4; ++q) {
        ra[q] = *reinterpret_cast<const uint4*>(gA[q] + koff);
        rb[q] = *reinterpret_cast<const uint4*>(gB[q] + koff);
      }
    }
    #pragma unroll
    for (int h = 0; h < 2; ++h) {
      bf16x8 af[4], bfr[4];
      #pragma unroll
      for (int f = 0; f < 4; ++f) {
        af[f]  = *reinterpret_cast<const bf16x8*>(cA + offA[f][h]);
        bfr[f] = *reinterpret_cast<const bf16x8*>(cB + offB[f][h]);
      }
      #pragma unroll
      for (int mf = 0; mf < 4; ++mf)
        #pragma unroll
        for (int nf = 0; nf < 4; ++nf)
          acc[mf][nf] = __builtin_amdgcn_mfma_f32_16x16x32_bf16(af[mf], bfr[nf], acc[mf][nf], 0, 0, 0);
    }
  }
}

// ---------------- MFMA jobs ----------------
__device__ void do_gemm1(const SP& p, int j, ushort* lsA, ushort* lsB) {
  const int bt = j / 25, nt = j % 25;
  const int m0 = bt * 128, n0 = nt * 128;
  f32x4 acc[4][4] = {};
  mfma_tile64<A1LD / 64>(p.A1 + (size_t)m0 * A1LD, A1LD, p.kwb + (size_t)n0 * A1LD, A1LD,
                         lsA, lsB, acc);
  const int lane = threadIdx.x & 63, wid = threadIdx.x >> 6;
  const int wm = (wid >> 1) * 64, wn = (wid & 1) * 64;
  const int lr = lane & 15, lg = lane >> 4;
  #pragma unroll
  for (int mf = 0; mf < 4; ++mf)
    #pragma unroll
    for (int nf = 0; nf < 4; ++nf) {
      int gc = n0 + wn + nf * 16 + lr;
      if (gc < Gg) {
        float zbv = p.zbias[gc];
        #pragma unroll
        for (int r = 0; r < 4; ++r) {
          int gr = m0 + wm + mf * 16 + lg * 4 + r;
          p.zb[(size_t)gr * Gg + gc] = f2bf(acc[mf][nf][r] + zbv);
        }
      }
    }
}

// fp8 conv job: 128x128 tile over K-split of 320 (5 chunks of 64 fp8 bytes)
__device__ void conv_job(const SP& p, int j, int t, ushort* lsAu, ushort* lsBu) {
  const int bt = j / (6 * SPLITS), r = j % (6 * SPLITS), ot = r / SPLITS, sp = r % SPLITS;
  const int m0 = bt * 128, o0 = ot * 128, k0 = sp * (KC / SPLITS);
  const unsigned char* A = p.ab8 + (size_t)m0 * KC + k0;
  const unsigned char* B = p.cwt8 + (size_t)o0 * KC + k0;
  char* cA = (char*)lsAu;
  char* cB = (char*)lsBu;
  const int tid = threadIdx.x;
  const int lane = tid & 63, wid = tid >> 6;
  const int wm = (wid >> 1) * 64, wn = (wid & 1) * 64;
  const int lr = lane & 15, lg = lane >> 4;
  int offA[4][2], offB[4][2];
  #pragma unroll
  for (int f = 0; f < 4; ++f) {
    int m = wm + f * 16 + lr;
    int n = wn + f * 16 + lr;
    #pragma unroll
    for (int h = 0; h < 2; ++h) {
      int s16 = h * 2 + (lg >> 1);
      offA[f][h] = m * 64 + ((s16 ^ (m & 3)) << 4) + (lg & 1) * 8;
      offB[f][h] = n * 64 + ((s16 ^ (n & 3)) << 4) + (lg & 1) * 8;
    }
  }
  int mrow[2], ldso[2];
  const unsigned char* gA[2];
  const unsigned char* gB[2];
  #pragma unroll
  for (int q = 0; q < 2; ++q) {
    int idx = q * 256 + tid;
    mrow[q] = idx >> 2;
    int s16 = idx & 3;
    ldso[q] = mrow[q] * 64 + ((s16 ^ (mrow[q] & 3)) << 4);
    gA[q] = A + (size_t)mrow[q] * KC + s16 * 16;
    gB[q] = B + (size_t)mrow[q] * KC + s16 * 16;
  }
  f32x4 acc[4][4] = {};
  uint4 ra[2], rb[2];
  #pragma unroll
  for (int q = 0; q < 2; ++q) {
    ra[q] = *reinterpret_cast<const uint4*>(gA[q]);
    rb[q] = *reinterpret_cast<const uint4*>(gB[q]);
  }
  constexpr int CHUNKS = (KC / SPLITS) / 64;   // 5
  for (int s = 0; s < CHUNKS; ++s) {
    __syncthreads();
    #pragma unroll
    for (int q = 0; q < 2; ++q) {
      *reinterpret_cast<uint4*>(cA + ldso[q]) = ra[q];
      *reinterpret_cast<uint4*>(cB + ldso[q]) = rb[q];
    }
    __syncthreads();
    if (s + 1 < CHUNKS) {
      int koff = (s + 1) * 64;
      #pragma unroll
      for (int q = 0; q < 2; ++q) {
        ra[q] = *reinterpret_cast<const uint4*>(gA[q] + koff);
        rb[q] = *reinterpret_cast<const uint4*>(gB[q] + koff);
      }
    }
    #pragma unroll
    for (int h = 0; h < 2; ++h) {
      long af[4], bfr[4];
      #pragma unroll
      for (int f = 0; f < 4; ++f) {
        af[f]  = *reinterpret_cast<const long*>(cA + offA[f][h]);
        bfr[f] = *reinterpret_cast<const long*>(cB + offB[f][h]);
      }
      #pragma unroll
      for (int mf = 0; mf < 4; ++mf)
        #pragma unroll
        for (int nf = 0; nf < 4; ++nf)
          acc[mf][nf] = __builtin_amdgcn_mfma_f32_16x16x32_fp8_fp8(af[mf], bfr[nf], acc[mf][nf], 0, 0, 0);
    }
  }
  float* dst = p.conv + (size_t)(t & 1) * (Bsz * Hh);
  #pragma unroll
  for (int mf = 0; mf < 4; ++mf)
    #pragma unroll
    for (int nf = 0; nf < 4; ++nf) {
      int gc = o0 + wn + nf * 16 + lr;
      #pragma unroll
      for (int rr = 0; rr < 4; ++rr) {
        int gr = m0 + wm + mf * 16 + lg * 4 + rr;
        unsafeAtomicAdd(&dst[(size_t)gr * Hh + gc], acc[mf][nf][rr]);
      }
    }
}

__device__ void th1_job(const SP& p, int j, ushort* lsA, ushort* lsB) {
  const int m0 = j * 128;
  f32x4 acc[4][4] = {};
  mfma_tile64<Hh / 64>(p.hmb + (size_t)m0 * Hh, Hh, p.swb, Hh, lsA, lsB, acc);
  const int lane = threadIdx.x & 63, wid = threadIdx.x >> 6;
  const int wm = (wid >> 1) * 64, wn = (wid & 1) * 64;
  const int lr = lane & 15, lg = lane >> 4;
  #pragma unroll
  for (int mf = 0; mf < 4; ++mf)
    #pragma unroll
    for (int nf = 0; nf < 4; ++nf) {
      int s = wn + nf * 16 + lr;
      float sb = p.sb[s];
      #pragma unroll
      for (int rr = 0; rr < 4; ++rr) {
        int gr = m0 + wm + mf * 16 + lg * 4 + rr;
        p.th1b[(size_t)gr * Ss + s] = f2bf(fmaxf(acc[mf][nf][rr] + sb, 0.f));
      }
    }
}

__device__ void theme2_job(const SP& p, int j, ushort* lsA, ushort* lsB) {
  const int mt = j / 6, nt = j % 6;
  const int m0 = mt * 128, n0 = nt * 128;
  f32x4 acc[4][4] = {};
  mfma_tile64<Ss / 64>(p.th1b + (size_t)m0 * Ss, Ss, p.rswb + (size_t)n0 * Ss, Ss, lsA, lsB, acc);
  const int lane = threadIdx.x & 63, wid = threadIdx.x >> 6;
  const int wm = (wid >> 1) * 64, wn = (wid & 1) * 64;
  const int lr = lane & 15, lg = lane >> 4;
  #pragma unroll
  for (int mf = 0; mf < 4; ++mf)
    #pragma unroll
    for (int nf = 0; nf < 4; ++nf) {
      int gc = n0 + wn + nf * 16 + lr;
      float rb = p.rsb[gc];
      #pragma unroll
      for (int rr = 0; rr < 4; ++rr) {
        int gr = m0 + wm + mf * 16 + lg * 4 + rr;
        p.theme2[(size_t)gr * Hh + gc] = sigf(acc[mf][nf][rr] + rb);
      }
    }
}

// ---------------- gates half-job: block handles H range [half*384, half*384+384) of row b ----------------
__device__ void gates_phase(const SP& p, int b, int half, int t, float* misc) {
  const int tid = threadIdx.x;
  float* sh  = misc;            // 768 (only own half used)
  float* sfm = misc + Hh;       // 8
  float* sim = misc + Hh + 8;   // 8
  float* sld = misc + Hh + 16;  // 10
  const int slot_t = t % Kw;
  const int i0 = half * (Hh / 2), i1 = i0 + (Hh / 2);
  if (tid == 0) {
    const ushort* zrow = p.zb + (size_t)b * Gg;
    float e[Ll], mx, ssum, inv, run;
    mx = -1e30f;
    for (int l = 0; l < Ll; ++l) mx = fmaxf(mx, bf2f(zrow[l]));
    ssum = 0.f;
    for (int l = 0; l < Ll; ++l) { e[l] = __expf(bf2f(zrow[l]) - mx); ssum += e[l]; }
    inv = 1.f / ssum; run = 0.f;
    float fmsum = 0.f;
    for (int l = 0; l < Ll; ++l) { run += e[l] * inv; sfm[l] = run; fmsum += run; }
    mx = -1e30f;
    for (int l = 0; l < Ll; ++l) mx = fmaxf(mx, bf2f(zrow[Ll + l]));
    ssum = 0.f;
    for (int l = 0; l < Ll; ++l) { e[l] = __expf(bf2f(zrow[Ll + l]) - mx); ssum += e[l]; }
    inv = 1.f / ssum; run = 0.f;
    for (int l = Ll - 1; l >= 0; --l) { run += e[l] * inv; sim[l] = run; }
    float cdis = 1.f - fmsum * (1.f / Ll);
    if (half == 0) p.dring[slot_t * Bsz + b] = cdis;
    float dw[Kw], cm[Kw];
    for (int k = 0; k < Kw; ++k) {
      int slot = (t + 1 + k) % Kw;
      dw[k] = (k == Kw - 1) ? cdis : p.dring[slot * Bsz + b];
    }
    float cs = 0.f, mx2 = -1e30f;
    for (int k = 0; k < Kw; ++k) { cs += dw[k]; cm[k] = cs; mx2 = fmaxf(mx2, cs); }
    float s2 = 0.f;
    for (int k = 0; k < Kw; ++k) { cm[k] = __expf(cm[k] - mx2); s2 += cm[k]; }
    float i2 = 1.f / s2;
    for (int k = 0; k < Kw; ++k) sld[k] = cm[k] * i2;
  }
  // zero this step's conv accumulator slice (consumed by conv_job atomics in P2(t))
  {
    float* cz = p.conv + (size_t)(t & 1) * (Bsz * Hh) + (size_t)b * Hh;
    for (int idx = i0 + tid; idx < i1; idx += NTHR) cz[idx] = 0.f;
  }
  __syncthreads();
  const ushort* zg = p.zb + (size_t)b * Gg + 2 * Ll;
  for (int idx = i0 + tid; idx < i1; idx += NTHR) {
    int l = idx / Cc;
    float f  = sigf(bf2f(zg[idx]));
    float ii = sigf(bf2f(zg[Hh + idx]));
    float oo = sigf(bf2f(zg[2 * Hh + idx]));
    float ci = tanhfast(bf2f(zg[3 * Hh + idx]));
    float cl = p.cbuf[(size_t)b * Hh + idx];
    float fm = sfm[l], im = sim[l], ov = fm * im;
    float cn = ov * (f * cl + ii * ci) + (fm - ov) * cl + (im - ov) * ci;
    float hn = oo * tanhfast(cn);
    p.cbuf[(size_t)b * Hh + idx] = cn;
    p.hring[(size_t)slot_t * (Bsz * Hh) + (size_t)b * Hh + idx] = hn;
    p.A1[(size_t)b * A1LD + Ff + idx] = f2bf(hn);
    sh[idx] = hn;
  }
  if (half == 0 && t + 1 < Tt && tid < Ff)
    p.A1[(size_t)b * A1LD + tid] = f2bf(p.x[(size_t)b * (Tt * Ff) + (size_t)(t + 1) * Ff + tid]);
  __syncthreads();
  for (int idx = i0 + tid; idx < i1; idx += NTHR) {
    float a = 0.f;
    #pragma unroll
    for (int k = 0; k < Kw; ++k) {
      int slot = (t + 1 + k) % Kw;
      float hv = (k == Kw - 1) ? sh[idx]
                               : p.hring[(size_t)slot * (Bsz * Hh) + (size_t)b * Hh + idx];
      float v = hv * sld[k];
      p.ab8[(size_t)b * KC + (size_t)k * Hh + idx] = f2fp8(v);
      a += v;
    }
    p.hmb[(size_t)b * Hh + idx] = f2bf(a * (1.f / Kw));
  }
}

// combine step tc: out[b][tc] = sigmoid( sum_o (theme2*conv + h)*ow + ob )
__device__ void combine_phase(const SP& p, int b0, int tc, float* misc) {
  const int tid = threadIdx.x;
  float* sred = misc;
  const int slot_t = tc % Kw;
  const float* cv = p.conv + (size_t)(tc & 1) * (Bsz * Hh);
  float d[4] = {0.f, 0.f, 0.f, 0.f};
  for (int o = tid; o < Hh; o += NTHR) {
    float oww = p.ow[o], cbv = p.cb[o];
    #pragma unroll
    for (int q = 0; q < 4; ++q) {
      int b = b0 + q;
      float c = cbv + cv[(size_t)b * Hh + o];
      float th = p.theme2[(size_t)b * Hh + o];
      float hv = p.hring[(size_t)slot_t * (Bsz * Hh) + (size_t)b * Hh + o];
      d[q] += (th * c + hv) * oww;
    }
  }
  #pragma unroll
  for (int q = 0; q < 4; ++q) {
    float v = d[q];
    for (int off = 32; off > 0; off >>= 1) v += __shfl_down(v, off);
    if ((tid & 63) == 0) sred[(tid >> 6) * 4 + q] = v;
  }
  __syncthreads();
  if (tid < 4) {
    float v = sred[tid] + sred[4 + tid] + sred[8 + tid] + sred[12 + tid];
    p.out[(size_t)(b0 + tid) * Tt + tc] = sigf(v + p.ob[0]);
  }
  __syncthreads();
}

// ---------------- phase dispatch ----------------
__device__ void p1_work(const SP& p, int t, int j, float* misc, ushort* lsA, ushort* lsB) {
  if (j < GATE_JOBS) gates_phase(p, j >> 1, j & 1, t, misc);
  else if (t > 0) theme2_job(p, j - GATE_JOBS, lsA, lsB);
}
__device__ void p2_work(const SP& p, int t, int j, float* misc, ushort* lsA, ushort* lsB) {
  if (j < G1_JOBS) { if (t + 1 < Tt) do_gemm1(p, j, lsA, lsB); }
  else if (j < G1_JOBS + TH1_JOBS) th1_job(p, j - G1_JOBS, lsA, lsB);
  else if (j < G1_JOBS + TH1_JOBS + CONV_JOBS) conv_job(p, j - G1_JOBS - TH1_JOBS, t, lsA, lsB);
  else if (t > 0) combine_phase(p, (j - G1_JOBS - TH1_JOBS - CONV_JOBS) * 4, t - 1, misc);
}

// ---------------- step kernels (stream-ordered) ----------------
__global__ void __launch_bounds__(NTHR, 3) k_p1(SP p, int t) {
  __shared__ ushort lsA[128 * 64];
  __shared__ ushort lsB[128 * 64];
  __shared__ float misc[Hh + 64];
  if (blockIdx.x < P1_JOBS) p1_work(p, t, blockIdx.x, misc, lsA, lsB);
}
__global__ void __launch_bounds__(NTHR, 3) k_p2(SP p, int t) {
  __shared__ ushort lsA[128 * 64];
  __shared__ ushort lsB[128 * 64];
  __shared__ float misc[Hh + 64];
  if (blockIdx.x < P2_JOBS) p2_work(p, t, blockIdx.x, misc, lsA, lsB);
}
__global__ void __launch_bounds__(NTHR, 3) k_pre(SP p) {
  __shared__ ushort lsA[128 * 64];
  __shared__ ushort lsB[128 * 64];
  do_gemm1(p, blockIdx.x, lsA, lsB);
}
__global__ void __launch_bounds__(NTHR, 3) k_tail1(SP p) {
  __shared__ ushort lsA[128 * 64];
  __shared__ ushort lsB[128 * 64];
  theme2_job(p, blockIdx.x, lsA, lsB);
}
__global__ void __launch_bounds__(NTHR, 3) k_tail2(SP p) {
  __shared__ float misc[Hh + 64];
  combine_phase(p, blockIdx.x * 4, Tt - 1, misc);
}

// ---------------- host entry ----------------
extern "C" void kernel_launch(void* const* d_in, const int* in_sizes, int n_in,
                              void* d_out, int out_size, void* d_ws, size_t ws_size,
                              hipStream_t stream) {
  (void)in_sizes; (void)n_in;
  SP p;
  p.x   = (const float*)d_in[0];
  p.kw  = (const float*)d_in[1];
  p.kb  = (const float*)d_in[2];
  p.rw  = (const float*)d_in[3];
  p.rb  = (const float*)d_in[4];
  p.sw  = (const float*)d_in[5];
  p.sb  = (const float*)d_in[6];
  p.rsw = (const float*)d_in[7];
  p.rsb = (const float*)d_in[8];
  p.cw  = (const float*)d_in[9];
  p.cb  = (const float*)d_in[10];
  p.ow  = (const float*)d_in[11];
  p.ob  = (const float*)d_in[12];
  float* ws = (float*)d_ws;
  p.zb = (ushort*)(ws + O_Z);
  p.zbias = ws + O_ZB; p.hring = ws + O_HR; p.cbuf = ws + O_CB;
  p.dring = ws + O_DR; p.theme2 = ws + O_T2; p.conv = ws + O_CV;
  ushort* wsb = (ushort*)(ws + O_BF);
  p.kwb = wsb + H_KWB;
  p.cwt8 = (unsigned char*)(wsb + H_CWT);
  p.swb = wsb + H_SWB; p.rswb = wsb + H_RSW;
  p.A1 = wsb + H_A1;
  p.ab8 = (unsigned char*)(wsb + H_AB);
  p.hmb = wsb + H_HM; p.th1b = wsb + H_T1B;
  p.out = (float*)d_out;

  if (ws_size < WS_FL * sizeof(float)) {
    k_fill<<<(out_size + NTHR - 1) / NTHR, NTHR, 0, stream>>>((float*)d_out, out_size, 0.5f);
    return;
  }

  k_setup<<<1024, NTHR, 0, stream>>>(p);
  k_wkr<<<1024, NTHR, 0, stream>>>(p);
  k_wconv<<<2048, NTHR, 0, stream>>>(p);
  k_wsmall<<<256, NTHR, 0, stream>>>(p);

  k_pre<<<G1_JOBS, NTHR, 0, stream>>>(p);                   // z(0)
  for (int t = 0; t < Tt; ++t) {
    k_p1<<<P1_JOBS, NTHR, 0, stream>>>(p, t);               // gates(t) || theme2(t-1)
    k_p2<<<P2_JOBS, NTHR, 0, stream>>>(p, t);               // z(t+1)+th1(t)+conv(t)+combine(t-1)
  }
  k_tail1<<<TH2_JOBS, NTHR, 0, stream>>>(p);                // theme2(399)
  k_tail2<<<COMB_JOBS, NTHR, 0, stream>>>(p);               // combine(399)
}